// Round 18
// baseline (421.342 us; speedup 1.0000x reference)
//
#include <hip/hip_runtime.h>
#include <hip/hip_bf16.h>

#define B_TOT 2048
#define N_CAP 200
#define D_DIM 256
#define NT    256
#define NW    4               // waves per block
#define CPW   50              // capsules per wave (200/4, exact)

__device__ __forceinline__ float bf_lo(unsigned u) { return __uint_as_float(u << 16); }
__device__ __forceinline__ float bf_hi(unsigned u) { return __uint_as_float(u & 0xffff0000u); }

__device__ __forceinline__ float wave_sum(float v) {
#pragma unroll
    for (int off = 32; off; off >>= 1) v += __shfl_xor(v, off);
    return v;
}

// Block sum WITHOUT leading barrier: caller must guarantee a __syncthreads()
// executed between the previous read of red[] and this call (WAR safety).
__device__ __forceinline__ float block_sum_nb(float v, float* red, int wave, int lane) {
    v = wave_sum(v);
    if (lane == 0) red[wave] = v;
    __syncthreads();
    float s = 0.f;
#pragma unroll
    for (int i = 0; i < NW; ++i) s += red[i];
    return s;
}

// Anchor = R17 (157us best). R18 sole delta: NT 512->256 (4 waves), CPW 50,
// LB(256,4). Rationale: u[50]=100 + 4-deep chunk (16) + temps ~122 <= the
// 128-VGPR tier LB(256,4) pins -> allocator MUST allocate ~128 (no 64-point
// to hide at), and 128 VGPR x 4 waves/EU -> 4 blocks/CU co-resident (vs 2).
// exp/c phases: 200/256 lanes active (vs 200/512). Same total VALU per CU.
// DO NOT: fuse agreement+einsum accumulators (R3/R4 spill), LB(...,8)
// (R9: 32 VGPR), per-capsule sched_barrier (R6), LDS-split u (R7),
// lane-select psel gather (R11 wrong c), phase-cut tails / inline e*inv
// (R12 +19us), 1024-thread blocks (R13 +16us), persistent+DMA prefetch
// (R14), two-pass normalize (R15), load/norm phase split (R16 neutral).
__global__ __launch_bounds__(NT, 4)
void dyr_kernel(const float* __restrict__ embeds,
                const float* __restrict__ weights,
                float* __restrict__ out_v,
                float* __restrict__ out_c)
{
    __shared__ float s_part[NW][D_DIM];   // 4 KB
    __shared__ float red[NW];
    __shared__ float b_lds[N_CAP];        // routing logits; wave w owns n==w (mod 4)
    __shared__ float w_lds[N_CAP];        // einsum weights c_n * inv_n
    __shared__ float inv_lds[N_CAP];      // 1 / max(||x_n||, 1e-12)

    const int b    = blockIdx.x;
    const int t    = threadIdx.x;
    const int wave = t >> 6;
    const int lane = t & 63;

    // ---- init logits ----
    if (t < N_CAP) b_lds[t] = weights[(size_t)b * N_CAP + t];

    // ---- Load embeds ONCE; RAW x -> bf16 regs; 1/||x|| -> LDS.
    // wave w, lane l holds capsule n = w + 4i, dims [4l, 4l+4).
    // Chunks of 4 in-flight float4 loads (peak regs ~122 <= 128). ----
    const float* eb = embeds + (size_t)b * (N_CAP * D_DIM) + lane * 4;

    uint2 u[CPW];   // 100 VGPRs, raw x packed bf16
#pragma unroll
    for (int cc = 0; cc < 13; ++cc) {      // 50 = 12*4 + 2
        const int base = cc * 4;
        const int cnt  = (cc == 12) ? 2 : 4;
        float4 xs[4];
#pragma unroll
        for (int j = 0; j < 4; ++j) {
            if (j < cnt)
                xs[j] = *reinterpret_cast<const float4*>(eb + (wave + (base + j) * NW) * D_DIM);
        }
#pragma unroll
        for (int j = 0; j < 4; ++j) {
            if (j < cnt) {
                const float4 x = xs[j];
                float ss = fmaf(x.x, x.x, fmaf(x.y, x.y, fmaf(x.z, x.z, x.w * x.w)));
                ss = wave_sum(ss);
                if (lane == 0)
                    inv_lds[wave + (base + j) * NW] = 1.0f / fmaxf(sqrtf(ss), 1e-12f);
                union { __hip_bfloat16 h[4]; uint2 q; } pk;
                pk.h[0] = __float2bfloat16(x.x);
                pk.h[1] = __float2bfloat16(x.y);
                pk.h[2] = __float2bfloat16(x.z);
                pk.h[3] = __float2bfloat16(x.w);
                u[base + j] = pk.q;
            }
        }
    }
    __syncthreads();   // inv_lds/b_lds visible; WAR-guard for first block_sum_nb

    // ---- 3 routing iterations (R17's exact phase layout) ----
    for (int r = 0; r < 3; ++r) {
        // softmax denominator (no max-subtraction; |b| <= ~8, fp32 exp safe)
        const float e  = (t < N_CAP) ? __expf(b_lds[t]) : 0.0f;
        const float es = block_sum_nb(e, red, wave, lane);          // B1
        const float cs = (float)N_CAP / es;
        if (t < N_CAP) {
            const float cv = e * cs;             // c_n = softmax * N
            w_lds[t] = cv * inv_lds[t];          // einsum weight (norm folded)
            if (r == 2) out_c[(size_t)b * N_CAP + t] = cv;
        }
        __syncthreads();                          // B2: w_lds visible

        // einsum partial: acc = sum_i w_i * x_i  (own capsules, w broadcast)
        float4 acc = make_float4(0.f, 0.f, 0.f, 0.f);
#pragma unroll
        for (int i = 0; i < CPW; ++i) {
            const float wn = w_lds[wave + NW * i];   // wave-uniform broadcast
            acc.x = fmaf(wn, bf_lo(u[i].x), acc.x);
            acc.y = fmaf(wn, bf_hi(u[i].x), acc.y);
            acc.z = fmaf(wn, bf_lo(u[i].y), acc.z);
            acc.w = fmaf(wn, bf_hi(u[i].y), acc.w);
        }
        *reinterpret_cast<float4*>(&s_part[wave][lane * 4]) = acc;
        __syncthreads();                          // B3: s_part visible

        // WAVE-REDUNDANT squash: one wave's 64 lanes span all 256 dims,
        // so wave_sum of |sd|^2 is the full ssn. No block reduce, no v_lds.
        float4 sd = make_float4(0.f, 0.f, 0.f, 0.f);
#pragma unroll
        for (int w = 0; w < NW; ++w) {
            const float4 p = *reinterpret_cast<const float4*>(&s_part[w][lane * 4]);
            sd.x += p.x; sd.y += p.y; sd.z += p.z; sd.w += p.w;
        }
        float ssn = fmaf(sd.x, sd.x, fmaf(sd.y, sd.y, fmaf(sd.z, sd.z, sd.w * sd.w)));
        ssn = wave_sum(ssn);
        const float scale = ssn / (1.0f + ssn) * rsqrtf(ssn + 1e-9f);
        const float4 vv = make_float4(scale * sd.x, scale * sd.y,
                                      scale * sd.z, scale * sd.w);

        if (r == 2) {
            if (wave == 0)
                *reinterpret_cast<float4*>(&out_v[(size_t)b * D_DIM + lane * 4]) = vv;
        } else {
            // agreement: b_n += (x_n . v) * inv_n  (lane-0 owner-slot update);
            // vv is in registers — no LDS read, no extra barrier before this.
#pragma unroll
            for (int i = 0; i < CPW; ++i) {
                float p = fmaf(bf_lo(u[i].x), vv.x,
                          fmaf(bf_hi(u[i].x), vv.y,
                          fmaf(bf_lo(u[i].y), vv.z,
                               bf_hi(u[i].y) * vv.w)));
                p = wave_sum(p);
                if (lane == 0) {
                    const int n = wave + NW * i;
                    b_lds[n] = fmaf(p, inv_lds[n], b_lds[n]);
                }
            }
            __syncthreads();                      // B4: b_lds visible for next iter
        }
    }
}

extern "C" void kernel_launch(void* const* d_in, const int* in_sizes, int n_in,
                              void* d_out, int out_size, void* d_ws, size_t ws_size,
                              hipStream_t stream) {
    const float* embeds  = (const float*)d_in[0];
    const float* weights = (const float*)d_in[1];
    float* out   = (float*)d_out;
    float* out_v = out;                                  // [2048, 256]
    float* out_c = out + (size_t)B_TOT * D_DIM;          // [2048, 200]

    dyr_kernel<<<B_TOT, NT, 0, stream>>>(embeds, weights, out_v, out_c);
}

// Round 19
// 166.334 us; speedup vs baseline: 2.5331x; 2.5331x over previous
//
#include <hip/hip_runtime.h>
#include <hip/hip_bf16.h>

#define B_TOT 2048
#define N_CAP 200
#define D_DIM 256
#define NT    512
#define NW    8               // waves per block
#define CPW   25              // capsules per wave (200/8, exact)
#define NB    2               // batches per block
#define GRID  (B_TOT / NB)    // 1024 blocks
#define PFI   8               // per-wave capsule slots served from prefetch (i<8 -> caps 0..63)

__device__ __forceinline__ float bf_lo(unsigned u) { return __uint_as_float(u << 16); }
__device__ __forceinline__ float bf_hi(unsigned u) { return __uint_as_float(u & 0xffff0000u); }

__device__ __forceinline__ float wave_sum(float v) {
#pragma unroll
    for (int off = 32; off; off >>= 1) v += __shfl_xor(v, off);
    return v;
}

// Routing barriers order ONLY LDS data -> wait lgkmcnt, NOT vmcnt. This keeps
// the cross-batch global_load_lds DMA in flight across the whole routing
// phase (__syncthreads would drain vmcnt(0) and serialize the prefetch).
__device__ __forceinline__ void lgkm_barrier() {
    asm volatile("s_waitcnt lgkmcnt(0)\n\ts_barrier" ::: "memory");
}
__device__ __forceinline__ void full_drain_barrier() {   // DMA arrival gate
    asm volatile("s_waitcnt vmcnt(0) lgkmcnt(0)\n\ts_barrier" ::: "memory");
}

// Block sum WITHOUT leading barrier (caller guarantees WAR order); internal
// barrier is lgkm-only so prefetch DMA stays in flight.
__device__ __forceinline__ float block_sum_nb(float v, float* red, int wave, int lane) {
    v = wave_sum(v);
    if (lane == 0) red[wave] = v;
    lgkm_barrier();
    float s = 0.f;
#pragma unroll
    for (int i = 0; i < NW; ++i) s += red[i];
    return s;
}

// DMA 64 KB (caps 0..63 of next batch, raw f32) -> pf. Linear layout:
// LDS dest = wave-uniform base + lane*16 (HW rule), global src per-lane.
// 8 rounds x 8 waves x 1 KB. Uses no VGPR results and no wave slots.
__device__ __forceinline__ void issue_prefetch(const float* __restrict__ slab,
                                               float* pf, int wave, int lane) {
    const char* gb = (const char*)slab;
    char* lb = (char*)pf;
#pragma unroll
    for (int rd = 0; rd < 8; ++rd) {
        const int off = rd * 8192 + wave * 1024;
        __builtin_amdgcn_global_load_lds(
            (const __attribute__((address_space(1))) void*)(gb + off + lane * 16),
            (__attribute__((address_space(3))) void*)(lb + off),
            16, 0, 0);
    }
}

// Anchor = R17 (157us best; load-duty-cycle bound: loads issue ~40% of time).
// R19 delta: NB=2 batches/block + 64-cap f32 DMA prefetch of b1 issued at
// k=0 routing start, riding under routing via lgkm-only barriers; k=1 reads
// caps 0..63 from LDS. LDS 74KB -> still 2 blocks/CU. Routing math/phase
// layout byte-identical to R17.
// DO NOT: fuse agreement+einsum accumulators (R3/R4 spill), LB(...,8) (R9:
// 32 VGPR), LB(256,4)+u[50] (R18: 64 VGPR + 845MB spill), per-capsule
// sched_barrier (R6), LDS-split u (R7), lane-select psel gather (R11),
// phase-cut tails (R12), 1024-thread blocks (R13), 1-block/CU persistent
// (R14), two-pass normalize (R15), load/norm split (R16 neutral).
__global__ __launch_bounds__(NT, 4)
void dyr_kernel(const float* __restrict__ embeds,
                const float* __restrict__ weights,
                float* __restrict__ out_v,
                float* __restrict__ out_c)
{
    __shared__ __align__(16) float pf[PFI * NW * D_DIM];   // 64 KB prefetch
    __shared__ float s_part[NW][D_DIM];                    // 8 KB
    __shared__ float red[NW];
    __shared__ float b_lds[N_CAP];
    __shared__ float w_lds[N_CAP];
    __shared__ float inv_lds[N_CAP];

    const int t    = threadIdx.x;
    const int wave = t >> 6;
    const int lane = t & 63;
    const int b0   = blockIdx.x * NB;

#pragma unroll
    for (int k = 0; k < NB; ++k) {
        const int b = b0 + k;
        const float* slab = embeds + (size_t)b * (N_CAP * D_DIM);

        if (k > 0) full_drain_barrier();   // prefetch arrived; pf readable by all

        // ---- init logits (thread t owns slot t; same-thread reuse -> no sync) ----
        if (t < N_CAP) b_lds[t] = weights[(size_t)b * N_CAP + t];

        // ---- acquire u: RAW x -> bf16 regs; 1/||x|| -> LDS.
        // wave w, lane l holds capsule n = w + 8i, dims [4l, 4l+4). ----
        uint2 u[CPW];   // 50 VGPRs
        const float* eb = slab + lane * 4;

        if (k == 0) {
            // all 25 caps from global: 5 chunks x 5 in-flight (R17 schedule)
#pragma unroll
            for (int cc = 0; cc < 5; ++cc) {
                float4 xs[5];
#pragma unroll
                for (int j = 0; j < 5; ++j) {
                    const int n = wave + (cc * 5 + j) * NW;
                    xs[j] = *reinterpret_cast<const float4*>(eb + n * D_DIM);
                }
#pragma unroll
                for (int j = 0; j < 5; ++j) {
                    const float4 x = xs[j];
                    float ss = fmaf(x.x, x.x, fmaf(x.y, x.y, fmaf(x.z, x.z, x.w * x.w)));
                    ss = wave_sum(ss);
                    if (lane == 0)
                        inv_lds[wave + (cc * 5 + j) * NW] = 1.0f / fmaxf(sqrtf(ss), 1e-12f);
                    union { __hip_bfloat16 h[4]; uint2 q; } pk;
                    pk.h[0] = __float2bfloat16(x.x);
                    pk.h[1] = __float2bfloat16(x.y);
                    pk.h[2] = __float2bfloat16(x.z);
                    pk.h[3] = __float2bfloat16(x.w);
                    u[cc * 5 + j] = pk.q;
                }
            }
        } else {
            // caps 0..63 (i<8) from LDS prefetch; caps 64..199 from global
#pragma unroll
            for (int i = 0; i < PFI; ++i) {
                const int n = wave + i * NW;
                const float4 x = *reinterpret_cast<const float4*>(&pf[n * D_DIM + lane * 4]);
                float ss = fmaf(x.x, x.x, fmaf(x.y, x.y, fmaf(x.z, x.z, x.w * x.w)));
                ss = wave_sum(ss);
                if (lane == 0) inv_lds[n] = 1.0f / fmaxf(sqrtf(ss), 1e-12f);
                union { __hip_bfloat16 h[4]; uint2 q; } pk;
                pk.h[0] = __float2bfloat16(x.x);
                pk.h[1] = __float2bfloat16(x.y);
                pk.h[2] = __float2bfloat16(x.z);
                pk.h[3] = __float2bfloat16(x.w);
                u[i] = pk.q;
            }
#pragma unroll
            for (int cc = 0; cc < 4; ++cc) {           // 17 = 5+5+5+2
                const int base = PFI + cc * 5;
                const int cnt  = (cc == 3) ? 2 : 5;
                float4 xs[5];
#pragma unroll
                for (int j = 0; j < 5; ++j) {
                    if (j < cnt)
                        xs[j] = *reinterpret_cast<const float4*>(eb + (wave + (base + j) * NW) * D_DIM);
                }
#pragma unroll
                for (int j = 0; j < 5; ++j) {
                    if (j < cnt) {
                        const float4 x = xs[j];
                        float ss = fmaf(x.x, x.x, fmaf(x.y, x.y, fmaf(x.z, x.z, x.w * x.w)));
                        ss = wave_sum(ss);
                        if (lane == 0)
                            inv_lds[wave + (base + j) * NW] = 1.0f / fmaxf(sqrtf(ss), 1e-12f);
                        union { __hip_bfloat16 h[4]; uint2 q; } pk;
                        pk.h[0] = __float2bfloat16(x.x);
                        pk.h[1] = __float2bfloat16(x.y);
                        pk.h[2] = __float2bfloat16(x.z);
                        pk.h[3] = __float2bfloat16(x.w);
                        u[base + j] = pk.q;
                    }
                }
            }
        }
        __syncthreads();   // inv_lds/b_lds visible (own loads already consumed)

        // issue next batch's prefetch NOW: it streams under the whole routing
        // phase because every barrier below is lgkm-only.
        if (k + 1 < NB)
            issue_prefetch(slab + N_CAP * D_DIM, pf, wave, lane);

        // ---- 3 routing iterations (R17's exact phase layout) ----
        for (int r = 0; r < 3; ++r) {
            const float e  = (t < N_CAP) ? __expf(b_lds[t]) : 0.0f;
            const float es = block_sum_nb(e, red, wave, lane);          // B1 (lgkm)
            const float cs = (float)N_CAP / es;
            if (t < N_CAP) {
                const float cv = e * cs;             // c_n = softmax * N
                w_lds[t] = cv * inv_lds[t];          // einsum weight (norm folded)
                if (r == 2) out_c[(size_t)b * N_CAP + t] = cv;
            }
            lgkm_barrier();                           // B2: w_lds visible

            float4 acc = make_float4(0.f, 0.f, 0.f, 0.f);
#pragma unroll
            for (int i = 0; i < CPW; ++i) {
                const float wn = w_lds[wave + NW * i];   // wave-uniform broadcast
                acc.x = fmaf(wn, bf_lo(u[i].x), acc.x);
                acc.y = fmaf(wn, bf_hi(u[i].x), acc.y);
                acc.z = fmaf(wn, bf_lo(u[i].y), acc.z);
                acc.w = fmaf(wn, bf_hi(u[i].y), acc.w);
            }
            *reinterpret_cast<float4*>(&s_part[wave][lane * 4]) = acc;
            lgkm_barrier();                           // B3: s_part visible

            // wave-redundant squash (R17): one wave spans all 256 dims
            float4 sd = make_float4(0.f, 0.f, 0.f, 0.f);
#pragma unroll
            for (int w = 0; w < NW; ++w) {
                const float4 p = *reinterpret_cast<const float4*>(&s_part[w][lane * 4]);
                sd.x += p.x; sd.y += p.y; sd.z += p.z; sd.w += p.w;
            }
            float ssn = fmaf(sd.x, sd.x, fmaf(sd.y, sd.y, fmaf(sd.z, sd.z, sd.w * sd.w)));
            ssn = wave_sum(ssn);
            const float scale = ssn / (1.0f + ssn) * rsqrtf(ssn + 1e-9f);
            const float4 vv = make_float4(scale * sd.x, scale * sd.y,
                                          scale * sd.z, scale * sd.w);

            if (r == 2) {
                if (wave == 0)
                    *reinterpret_cast<float4*>(&out_v[(size_t)b * D_DIM + lane * 4]) = vv;
            } else {
                // agreement: b_n += (x_n . v) * inv_n (lane-0 owner-slot update)
#pragma unroll
                for (int i = 0; i < CPW; ++i) {
                    float p = fmaf(bf_lo(u[i].x), vv.x,
                              fmaf(bf_hi(u[i].x), vv.y,
                              fmaf(bf_lo(u[i].y), vv.z,
                                   bf_hi(u[i].y) * vv.w)));
                    p = wave_sum(p);
                    if (lane == 0) {
                        const int n = wave + NW * i;
                        b_lds[n] = fmaf(p, inv_lds[n], b_lds[n]);
                    }
                }
                lgkm_barrier();                       // B4: b_lds visible
            }
        }
    }
}

extern "C" void kernel_launch(void* const* d_in, const int* in_sizes, int n_in,
                              void* d_out, int out_size, void* d_ws, size_t ws_size,
                              hipStream_t stream) {
    const float* embeds  = (const float*)d_in[0];
    const float* weights = (const float*)d_in[1];
    float* out   = (float*)d_out;
    float* out_v = out;                                  // [2048, 256]
    float* out_c = out + (size_t)B_TOT * D_DIM;          // [2048, 200]

    dyr_kernel<<<GRID, NT, 0, stream>>>(embeds, weights, out_v, out_c);
}

// Round 20
// 156.996 us; speedup vs baseline: 2.6838x; 1.0595x over previous
//
#include <hip/hip_runtime.h>
#include <hip/hip_bf16.h>

#define B_TOT 2048
#define N_CAP 200
#define D_DIM 256
#define NT    512
#define NW    8               // waves per block
#define CPW   25              // capsules per wave (200/8, exact)

__device__ __forceinline__ float bf_lo(unsigned u) { return __uint_as_float(u << 16); }
__device__ __forceinline__ float bf_hi(unsigned u) { return __uint_as_float(u & 0xffff0000u); }

__device__ __forceinline__ float wave_sum(float v) {
#pragma unroll
    for (int off = 32; off; off >>= 1) v += __shfl_xor(v, off);
    return v;
}

// Block sum WITHOUT leading barrier: caller must guarantee a __syncthreads()
// executed between the previous read of red[] and this call (WAR safety).
__device__ __forceinline__ float block_sum_nb(float v, float* red, int wave, int lane) {
    v = wave_sum(v);
    if (lane == 0) red[wave] = v;
    __syncthreads();
    float s = 0.f;
#pragma unroll
    for (int i = 0; i < NW; ++i) s += red[i];
    return s;
}

// FINAL = R17 (157us, best of 20 rounds). Structure: one block per batch b;
// u_hat kept as raw bf16 in registers (u[25], 50 VGPRs); 1/||x|| in LDS with
// the norm folded into the einsum weight w_n = c_n*inv_n; 5x5-deep load
// chunks; wave-redundant squash (one wave's 64 lanes span all 256 dims, so
// wave_sum(|sd|^2) is the full norm - no block reduce, no v_lds); 11
// barriers total.
// Probes that LOST to this (do not retry): fused agreement+einsum accums
// (R3/R4: allocator's 64-VGPR point + 300MB spill), LB(...,8) (R9: 32 VGPR
// wholesale spill), LB(256,4)+u[50] (R18: 64 VGPR + 845MB spill),
// per-capsule sched_barrier (R6: depth-1 loads), LDS-split u (R7),
// lane-select psel gather (R11: wrong c), phase-cut tails / inline e*inv
// (R12: +19us), 1024-thread blocks (R13: +16us), persistent blocks + DMA
// prefetch (R14: +85us), two-pass normalize (R15: +43us), load/norm phase
// split (R16: neutral), lgkm-only barriers + cross-batch DMA (R19: +9us).
__global__ __launch_bounds__(NT, 4)
void dyr_kernel(const float* __restrict__ embeds,
                const float* __restrict__ weights,
                float* __restrict__ out_v,
                float* __restrict__ out_c)
{
    __shared__ float s_part[NW][D_DIM];   // 8 KB
    __shared__ float red[NW];
    __shared__ float b_lds[N_CAP];        // routing logits
    __shared__ float w_lds[N_CAP];        // einsum weights c_n * inv_n
    __shared__ float inv_lds[N_CAP];      // 1 / max(||x_n||, 1e-12)

    const int b    = blockIdx.x;
    const int t    = threadIdx.x;
    const int wave = t >> 6;
    const int lane = t & 63;

    // ---- init logits ----
    if (t < N_CAP) b_lds[t] = weights[(size_t)b * N_CAP + t];

    // ---- Load embeds ONCE; RAW x -> bf16 regs; 1/||x|| -> LDS.
    // wave w, lane l holds capsule n = w + 8i, dims [4l, 4l+4).
    // 5 chunks x 5 in-flight float4 loads. ----
    const float* eb = embeds + (size_t)b * (N_CAP * D_DIM) + lane * 4;

    uint2 u[CPW];   // 50 VGPRs, raw x packed bf16
#pragma unroll
    for (int cc = 0; cc < 5; ++cc) {
        float4 xs[5];
#pragma unroll
        for (int j = 0; j < 5; ++j) {
            const int n = wave + (cc * 5 + j) * NW;
            xs[j] = *reinterpret_cast<const float4*>(eb + n * D_DIM);
        }
#pragma unroll
        for (int j = 0; j < 5; ++j) {
            const float4 x = xs[j];
            float ss = fmaf(x.x, x.x, fmaf(x.y, x.y, fmaf(x.z, x.z, x.w * x.w)));
            ss = wave_sum(ss);
            if (lane == 0)
                inv_lds[wave + (cc * 5 + j) * NW] = 1.0f / fmaxf(sqrtf(ss), 1e-12f);
            union { __hip_bfloat16 h[4]; uint2 q; } pk;
            pk.h[0] = __float2bfloat16(x.x);
            pk.h[1] = __float2bfloat16(x.y);
            pk.h[2] = __float2bfloat16(x.z);
            pk.h[3] = __float2bfloat16(x.w);
            u[cc * 5 + j] = pk.q;
        }
    }
    __syncthreads();   // inv_lds/b_lds visible; WAR-guard for first block_sum_nb

    // ---- 3 routing iterations ----
    for (int r = 0; r < 3; ++r) {
        // softmax denominator (no max-subtraction; |b| <= ~8, fp32 exp safe)
        const float e  = (t < N_CAP) ? __expf(b_lds[t]) : 0.0f;
        const float es = block_sum_nb(e, red, wave, lane);          // B1
        const float cs = (float)N_CAP / es;
        if (t < N_CAP) {
            const float cv = e * cs;             // c_n = softmax * N
            w_lds[t] = cv * inv_lds[t];          // einsum weight (norm folded)
            if (r == 2) out_c[(size_t)b * N_CAP + t] = cv;
        }
        __syncthreads();                          // B2: w_lds visible

        // einsum partial: acc = sum_i w_i * x_i  (own capsules, w broadcast)
        float4 acc = make_float4(0.f, 0.f, 0.f, 0.f);
#pragma unroll
        for (int i = 0; i < CPW; ++i) {
            const float wn = w_lds[wave + NW * i];   // wave-uniform broadcast
            acc.x = fmaf(wn, bf_lo(u[i].x), acc.x);
            acc.y = fmaf(wn, bf_hi(u[i].x), acc.y);
            acc.z = fmaf(wn, bf_lo(u[i].y), acc.z);
            acc.w = fmaf(wn, bf_hi(u[i].y), acc.w);
        }
        *reinterpret_cast<float4*>(&s_part[wave][lane * 4]) = acc;
        __syncthreads();                          // B3: s_part visible

        // WAVE-REDUNDANT squash: this wave's 64 lanes span all 256 dims,
        // so wave_sum of |sd|^2 is the full ssn. No block reduce, no v_lds.
        float4 sd = make_float4(0.f, 0.f, 0.f, 0.f);
#pragma unroll
        for (int w = 0; w < NW; ++w) {
            const float4 p = *reinterpret_cast<const float4*>(&s_part[w][lane * 4]);
            sd.x += p.x; sd.y += p.y; sd.z += p.z; sd.w += p.w;
        }
        float ssn = fmaf(sd.x, sd.x, fmaf(sd.y, sd.y, fmaf(sd.z, sd.z, sd.w * sd.w)));
        ssn = wave_sum(ssn);
        const float scale = ssn / (1.0f + ssn) * rsqrtf(ssn + 1e-9f);
        const float4 vv = make_float4(scale * sd.x, scale * sd.y,
                                      scale * sd.z, scale * sd.w);

        if (r == 2) {
            if (wave == 0)
                *reinterpret_cast<float4*>(&out_v[(size_t)b * D_DIM + lane * 4]) = vv;
        } else {
            // agreement: b_n += (x_n . v) * inv_n  (lane-0 owner-slot update);
            // vv is in registers — no LDS read, no extra barrier before this.
#pragma unroll
            for (int i = 0; i < CPW; ++i) {
                float p = fmaf(bf_lo(u[i].x), vv.x,
                          fmaf(bf_hi(u[i].x), vv.y,
                          fmaf(bf_lo(u[i].y), vv.z,
                               bf_hi(u[i].y) * vv.w)));
                p = wave_sum(p);
                if (lane == 0) {
                    const int n = wave + NW * i;
                    b_lds[n] = fmaf(p, inv_lds[n], b_lds[n]);
                }
            }
            __syncthreads();                      // B4: b_lds visible for next iter
        }
    }
}

extern "C" void kernel_launch(void* const* d_in, const int* in_sizes, int n_in,
                              void* d_out, int out_size, void* d_ws, size_t ws_size,
                              hipStream_t stream) {
    const float* embeds  = (const float*)d_in[0];
    const float* weights = (const float*)d_in[1];
    float* out   = (float*)d_out;
    float* out_v = out;                                  // [2048, 256]
    float* out_c = out + (size_t)B_TOT * D_DIM;          // [2048, 200]

    dyr_kernel<<<B_TOT, NT, 0, stream>>>(embeds, weights, out_v, out_c);
}

// Round 22
// 103.869 us; speedup vs baseline: 4.0565x; 1.5115x over previous
//
#include <hip/hip_runtime.h>
#include <hip/hip_bf16.h>

#define B_TOT 2048
#define N_CAP 200
#define D_DIM 256
#define NT    512
#define NW    8               // waves per block
#define CPW   25              // capsules per wave (200/8, exact)

__device__ __forceinline__ float bf_lo(unsigned u) { return __uint_as_float(u << 16); }
__device__ __forceinline__ float bf_hi(unsigned u) { return __uint_as_float(u & 0xffff0000u); }

// ---- DPP wave reduction (R21 delta; R22: ctrl/rmask as template constants,
// __builtin_amdgcn_update_dpp requires constant-integer args) ----------------
// Classic GCN ladder: row_shr 1/2/4/8 then row_bcast15 (rows 1,3) and
// row_bcast31 (rows 2,3), zero-fill for invalid lanes. 6 pure-VALU ops, no
// LDS pipe (vs __shfl_xor = 6 dependent ds_bpermute round-trips). Full sum
// lands in LANE 63; bcast63() broadcasts it via readlane (SGPR, uniform).
template <int CTRL, int RMASK>
__device__ __forceinline__ float dpp_term(float v) {
    return __int_as_float(__builtin_amdgcn_update_dpp(
        0, __float_as_int(v), CTRL, RMASK, 0xf, true));
}
__device__ __forceinline__ float wave_red63(float v) {
    v += dpp_term<0x111, 0xf>(v);   // row_shr:1
    v += dpp_term<0x112, 0xf>(v);   // row_shr:2
    v += dpp_term<0x114, 0xf>(v);   // row_shr:4
    v += dpp_term<0x118, 0xf>(v);   // row_shr:8  -> lane 15 of each row = row sum
    v += dpp_term<0x142, 0xa>(v);   // row_bcast15 -> rows 1,3 accumulate
    v += dpp_term<0x143, 0xc>(v);   // row_bcast31 -> lane 63 = full sum
    return v;
}
__device__ __forceinline__ float bcast63(float v) {
    return __int_as_float(__builtin_amdgcn_readlane(__float_as_int(v), 63));
}

// Block sum WITHOUT leading barrier: caller must guarantee a __syncthreads()
// executed between the previous read of red[] and this call (WAR safety).
// Lane 63 (DPP sum holder) publishes the wave partial.
__device__ __forceinline__ float block_sum_nb(float v, float* red, int wave, int lane) {
    v = wave_red63(v);
    if (lane == 63) red[wave] = v;
    __syncthreads();
    float s = 0.f;
#pragma unroll
    for (int i = 0; i < NW; ++i) s += red[i];
    return s;
}

// Anchor = R17/R20 (157us, best). R21/R22 sole delta: every wave reduction
// uses the DPP ladder (VALU) instead of __shfl_xor (ds_bpermute, LDS pipe);
// ~81 reductions/block x 6 LDS round-trips moved off the LDS critical path.
// Consumers: LDS writers lane==0 -> lane==63; squash scale via readlane(63).
// Phases, barriers, load schedule, register shape: byte-identical to R17.
// Probes that LOST (do not retry): fused agreement+einsum accums (R3/R4
// spill), LB(...,8) (R9), LB(256,4)+u[50] (R18), per-capsule sched_barrier
// (R6), LDS-split u (R7), lane-select psel gather (R11 wrong c), phase-cut
// tails (R12), 1024-thr blocks (R13), persistent+DMA (R14), two-pass norm
// (R15), load/norm split (R16 neutral), lgkm-only barriers + DMA (R19).
__global__ __launch_bounds__(NT, 4)
void dyr_kernel(const float* __restrict__ embeds,
                const float* __restrict__ weights,
                float* __restrict__ out_v,
                float* __restrict__ out_c)
{
    __shared__ float s_part[NW][D_DIM];   // 8 KB
    __shared__ float red[NW];
    __shared__ float b_lds[N_CAP];        // routing logits
    __shared__ float w_lds[N_CAP];        // einsum weights c_n * inv_n
    __shared__ float inv_lds[N_CAP];      // 1 / max(||x_n||, 1e-12)

    const int b    = blockIdx.x;
    const int t    = threadIdx.x;
    const int wave = t >> 6;
    const int lane = t & 63;

    // ---- init logits ----
    if (t < N_CAP) b_lds[t] = weights[(size_t)b * N_CAP + t];

    // ---- Load embeds ONCE; RAW x -> bf16 regs; 1/||x|| -> LDS.
    // wave w, lane l holds capsule n = w + 8i, dims [4l, 4l+4).
    // 5 chunks x 5 in-flight float4 loads (proven schedule). ----
    const float* eb = embeds + (size_t)b * (N_CAP * D_DIM) + lane * 4;

    uint2 u[CPW];   // 50 VGPRs, raw x packed bf16
#pragma unroll
    for (int cc = 0; cc < 5; ++cc) {
        float4 xs[5];
#pragma unroll
        for (int j = 0; j < 5; ++j) {
            const int n = wave + (cc * 5 + j) * NW;
            xs[j] = *reinterpret_cast<const float4*>(eb + n * D_DIM);
        }
#pragma unroll
        for (int j = 0; j < 5; ++j) {
            const float4 x = xs[j];
            float ss = fmaf(x.x, x.x, fmaf(x.y, x.y, fmaf(x.z, x.z, x.w * x.w)));
            ss = wave_red63(ss);
            if (lane == 63)
                inv_lds[wave + (cc * 5 + j) * NW] = 1.0f / fmaxf(sqrtf(ss), 1e-12f);
            union { __hip_bfloat16 h[4]; uint2 q; } pk;
            pk.h[0] = __float2bfloat16(x.x);
            pk.h[1] = __float2bfloat16(x.y);
            pk.h[2] = __float2bfloat16(x.z);
            pk.h[3] = __float2bfloat16(x.w);
            u[cc * 5 + j] = pk.q;
        }
    }
    __syncthreads();   // inv_lds/b_lds visible; WAR-guard for first block_sum_nb

    // ---- 3 routing iterations ----
    for (int r = 0; r < 3; ++r) {
        // softmax denominator (no max-subtraction; |b| <= ~8, fp32 exp safe)
        const float e  = (t < N_CAP) ? __expf(b_lds[t]) : 0.0f;
        const float es = block_sum_nb(e, red, wave, lane);          // B1
        const float cs = (float)N_CAP / es;
        if (t < N_CAP) {
            const float cv = e * cs;             // c_n = softmax * N
            w_lds[t] = cv * inv_lds[t];          // einsum weight (norm folded)
            if (r == 2) out_c[(size_t)b * N_CAP + t] = cv;
        }
        __syncthreads();                          // B2: w_lds visible

        // einsum partial: acc = sum_i w_i * x_i  (own capsules, w broadcast)
        float4 acc = make_float4(0.f, 0.f, 0.f, 0.f);
#pragma unroll
        for (int i = 0; i < CPW; ++i) {
            const float wn = w_lds[wave + NW * i];   // wave-uniform broadcast
            acc.x = fmaf(wn, bf_lo(u[i].x), acc.x);
            acc.y = fmaf(wn, bf_hi(u[i].x), acc.y);
            acc.z = fmaf(wn, bf_lo(u[i].y), acc.z);
            acc.w = fmaf(wn, bf_hi(u[i].y), acc.w);
        }
        *reinterpret_cast<float4*>(&s_part[wave][lane * 4]) = acc;
        __syncthreads();                          // B3: s_part visible

        // WAVE-REDUNDANT squash: this wave's 64 lanes span all 256 dims,
        // so the wave reduction of |sd|^2 is the full ssn (readlane bcast).
        float4 sd = make_float4(0.f, 0.f, 0.f, 0.f);
#pragma unroll
        for (int w = 0; w < NW; ++w) {
            const float4 p = *reinterpret_cast<const float4*>(&s_part[w][lane * 4]);
            sd.x += p.x; sd.y += p.y; sd.z += p.z; sd.w += p.w;
        }
        float ssn = fmaf(sd.x, sd.x, fmaf(sd.y, sd.y, fmaf(sd.z, sd.z, sd.w * sd.w)));
        ssn = bcast63(wave_red63(ssn));
        const float scale = ssn / (1.0f + ssn) * rsqrtf(ssn + 1e-9f);
        const float4 vv = make_float4(scale * sd.x, scale * sd.y,
                                      scale * sd.z, scale * sd.w);

        if (r == 2) {
            if (wave == 0)
                *reinterpret_cast<float4*>(&out_v[(size_t)b * D_DIM + lane * 4]) = vv;
        } else {
            // agreement: b_n += (x_n . v) * inv_n  (lane-63 owner-slot update);
            // vv is in registers — no LDS read, no extra barrier before this.
#pragma unroll
            for (int i = 0; i < CPW; ++i) {
                float p = fmaf(bf_lo(u[i].x), vv.x,
                          fmaf(bf_hi(u[i].x), vv.y,
                          fmaf(bf_lo(u[i].y), vv.z,
                               bf_hi(u[i].y) * vv.w)));
                p = wave_red63(p);
                if (lane == 63) {
                    const int n = wave + NW * i;
                    b_lds[n] = fmaf(p, inv_lds[n], b_lds[n]);
                }
            }
            __syncthreads();                      // B4: b_lds visible for next iter
        }
    }
}

extern "C" void kernel_launch(void* const* d_in, const int* in_sizes, int n_in,
                              void* d_out, int out_size, void* d_ws, size_t ws_size,
                              hipStream_t stream) {
    const float* embeds  = (const float*)d_in[0];
    const float* weights = (const float*)d_in[1];
    float* out   = (float*)d_out;
    float* out_v = out;                                  // [2048, 256]
    float* out_c = out + (size_t)B_TOT * D_DIM;          // [2048, 200]

    dyr_kernel<<<B_TOT, NT, 0, stream>>>(embeds, weights, out_v, out_c);
}